// Round 13
// baseline (318.663 us; speedup 1.0000x reference)
//
#include <hip/hip_runtime.h>
#include <cstddef>
#include <cstdint>

#define Lseq   2048
#define Dmodel 1024
#define NGRP   32          // B*H
#define MROWS  4096        // B*L
#define EPS_LN 1e-5f

typedef short  s16x8 __attribute__((ext_vector_type(8)));
typedef float  f32x4 __attribute__((ext_vector_type(4)));
typedef unsigned short ushort_t;

__device__ __forceinline__ ushort_t f2bf(float f) {
    union { float f; unsigned u; } v; v.f = f;
    unsigned r = v.u + 0x7FFFu + ((v.u >> 16) & 1u);   // round-to-nearest-even
    return (ushort_t)(r >> 16);
}

// packed f32x2 -> bf16x2 (RTNE, same rounding as f2bf)
__device__ __forceinline__ unsigned cvt_pk_bf16(float lo, float hi) {
    unsigned r;
    asm("v_cvt_pk_bf16_f32 %0, %1, %2" : "=v"(r) : "v"(lo), "v"(hi));
    return r;
}

// CK-idiom addrspace casts (uintptr round-trip; folded by InferAddressSpaces)
__device__ __forceinline__ void gld16(const ushort_t* g, ushort_t* lds) {
    __builtin_amdgcn_global_load_lds(
        (const __attribute__((address_space(1))) unsigned int*)(uintptr_t)g,
        (__attribute__((address_space(3))) unsigned int*)(uintptr_t)lds,
        16, 0, 0);
}

// XCD-chunked bijective remap for a 32-wide index at gridX=8-residue:
// XCD k (= f mod 8) owns values 4k..4k+3
__device__ __forceinline__ int xcd_chunk32(int f) {
    return (f & 7) * 4 + ((f >> 3) & 3);
}

// PV k-slot permutation: slot s within a 64-key chunk holds key perm64(s).
// Derived from the register-resident P layout after swapped QK^T:
//   lane (lg,lr), a-frag elem e -> key 32kk + (e>=4)*16 + 4lg + (e&3)
// MFMA contraction is k-permutation-invariant when A and B agree.
__device__ __forceinline__ int perm64(int s) {
    return (s & 32) + ((s & 4) << 2) + (((s >> 3) & 3) << 2) + (s & 3);
}

// ---------------------------------------------------------------------------
// Pre-convert fp32 -> bf16 for Q/K/V inputs and the 4 weight matrices.
// ---------------------------------------------------------------------------
struct CvtArgs {
    const float* src[7];
    ushort_t*    dst[7];
    int          n8[7];
};

__global__ __launch_bounds__(256) void cvt_bf16(CvtArgs a)
{
    const int ti = blockIdx.y;
    const float* __restrict__ s = a.src[ti];
    ushort_t* __restrict__    d = a.dst[ti];
    const int n8 = a.n8[ti];
    for (int i = blockIdx.x * 256 + threadIdx.x; i < n8; i += gridDim.x * 256) {
        float4 x0 = reinterpret_cast<const float4*>(s)[i * 2];
        float4 x1 = reinterpret_cast<const float4*>(s)[i * 2 + 1];
        s16x8 o;
        o[0]=f2bf(x0.x); o[1]=f2bf(x0.y); o[2]=f2bf(x0.z); o[3]=f2bf(x0.w);
        o[4]=f2bf(x1.x); o[5]=f2bf(x1.y); o[6]=f2bf(x1.z); o[7]=f2bf(x1.w);
        reinterpret_cast<s16x8*>(d)[i] = o;
    }
}

// ---------------------------------------------------------------------------
// QKV GEMM: out[M,N] = A[M,1024] @ W[N,1024]^T + bias, bf16 out.
// Tile 128x128, BK=64, 32 KB LDS. grid (256,1,3), XCD-chunked m-tiles.
// ---------------------------------------------------------------------------
struct QkvArgs {
    const ushort_t* A[3];
    const ushort_t* W[3];
    const float*    bias[3];
    ushort_t*       out[3];
};

__global__ __launch_bounds__(256) void gemm_qkv(QkvArgs a)
{
    __shared__ ushort_t As[128 * 64];   // 16 KB
    __shared__ ushort_t Bs[128 * 64];   // 16 KB
    const int z  = blockIdx.z;
    const int f  = blockIdx.x;
    const int m0 = xcd_chunk32(f) * 128;
    const int n0 = (f >> 5) * 128;

    const ushort_t* __restrict__ A = a.A[z];
    const ushort_t* __restrict__ W = a.W[z];
    const float*    __restrict__ bias = a.bias[z];
    ushort_t*       __restrict__ outv = a.out[z];

    const int t  = threadIdx.x;
    const int w  = t >> 6;
    const int l  = t & 63;
    const int lr = l & 15;
    const int lg = l >> 4;
    const int wm = w >> 1, wn = w & 1;

    const ushort_t* gA = A + (size_t)(m0 + w * 32 + (l >> 3)) * 1024 + (l & 7) * 8;
    const ushort_t* gB = W + (size_t)(n0 + w * 32 + (l >> 3)) * 1024 + (l & 7) * 8;
    ushort_t* lA = &As[(w * 32) * 64];
    ushort_t* lB = &Bs[(w * 32) * 64];

    f32x4 acc[4][4] = {};

    for (int k0 = 0; k0 < 1024; k0 += 64) {
#pragma unroll
        for (int j = 0; j < 4; ++j) {
            gld16(gA + (size_t)j * 8 * 1024 + k0, lA + j * 8 * 64);
            gld16(gB + (size_t)j * 8 * 1024 + k0, lB + j * 8 * 64);
        }
        __syncthreads();

#pragma unroll
        for (int kk = 0; kk < 2; ++kk) {
            s16x8 af[4], bf[4];
#pragma unroll
            for (int mi = 0; mi < 4; ++mi)
                af[mi] = *reinterpret_cast<const s16x8*>(&As[(wm * 64 + mi * 16 + lr) * 64 + kk * 32 + lg * 8]);
#pragma unroll
            for (int ni = 0; ni < 4; ++ni)
                bf[ni] = *reinterpret_cast<const s16x8*>(&Bs[(wn * 64 + ni * 16 + lr) * 64 + kk * 32 + lg * 8]);
#pragma unroll
            for (int mi = 0; mi < 4; ++mi)
#pragma unroll
                for (int ni = 0; ni < 4; ++ni)
                    acc[mi][ni] = __builtin_amdgcn_mfma_f32_16x16x32_bf16(af[mi], bf[ni], acc[mi][ni], 0, 0, 0);
        }
        __syncthreads();
    }

#pragma unroll
    for (int mi = 0; mi < 4; ++mi)
#pragma unroll
        for (int ni = 0; ni < 4; ++ni)
#pragma unroll
            for (int r = 0; r < 4; ++r) {
                int row = m0 + wm * 64 + mi * 16 + lg * 4 + r;
                int col = n0 + wn * 64 + ni * 16 + lr;
                outv[(size_t)row * 1024 + col] = f2bf(acc[mi][ni][r] + bias[col]);
            }
}

// ---------------------------------------------------------------------------
// Output GEMM: 64x128 tile, BK=64, fp32 out with bias+residual. 512 blocks.
// ---------------------------------------------------------------------------
__global__ __launch_bounds__(256) void gemm_o(
    const ushort_t* __restrict__ A, const ushort_t* __restrict__ W,
    const float* __restrict__ bias, const float* __restrict__ resid,
    float* __restrict__ out)
{
    __shared__ ushort_t As[64 * 64];    //  8 KB
    __shared__ ushort_t Bs[128 * 64];   // 16 KB

    const int f  = blockIdx.x;                              // 0..511
    const int m0 = ((f & 7) * 8 + ((f >> 3) & 7)) * 64;     // 64 m-tiles
    const int n0 = (f >> 6) * 128;                          // 8 n-tiles

    const int t  = threadIdx.x;
    const int w  = t >> 6;
    const int l  = t & 63;
    const int lr = l & 15;
    const int lg = l >> 4;
    const int wm = w >> 1, wn = w & 1;    // wave tile 32x64

    const ushort_t* gA = A + (size_t)(m0 + w * 16 + (l >> 3)) * 1024 + (l & 7) * 8;
    const ushort_t* gB = W + (size_t)(n0 + w * 32 + (l >> 3)) * 1024 + (l & 7) * 8;
    ushort_t* lA = &As[(w * 16) * 64];
    ushort_t* lB = &Bs[(w * 32) * 64];

    f32x4 acc[2][4] = {};

    for (int k0 = 0; k0 < 1024; k0 += 64) {
#pragma unroll
        for (int j = 0; j < 2; ++j)
            gld16(gA + (size_t)j * 8 * 1024 + k0, lA + j * 8 * 64);
#pragma unroll
        for (int j = 0; j < 4; ++j)
            gld16(gB + (size_t)j * 8 * 1024 + k0, lB + j * 8 * 64);
        __syncthreads();

#pragma unroll
        for (int kk = 0; kk < 2; ++kk) {
            s16x8 af[2], bf[4];
#pragma unroll
            for (int mi = 0; mi < 2; ++mi)
                af[mi] = *reinterpret_cast<const s16x8*>(&As[(wm * 32 + mi * 16 + lr) * 64 + kk * 32 + lg * 8]);
#pragma unroll
            for (int ni = 0; ni < 4; ++ni)
                bf[ni] = *reinterpret_cast<const s16x8*>(&Bs[(wn * 64 + ni * 16 + lr) * 64 + kk * 32 + lg * 8]);
#pragma unroll
            for (int mi = 0; mi < 2; ++mi)
#pragma unroll
                for (int ni = 0; ni < 4; ++ni)
                    acc[mi][ni] = __builtin_amdgcn_mfma_f32_16x16x32_bf16(af[mi], bf[ni], acc[mi][ni], 0, 0, 0);
        }
        __syncthreads();
    }

#pragma unroll
    for (int mi = 0; mi < 2; ++mi)
#pragma unroll
        for (int ni = 0; ni < 4; ++ni)
#pragma unroll
            for (int r = 0; r < 4; ++r) {
                int row = m0 + wm * 32 + mi * 16 + lg * 4 + r;
                int col = n0 + wn * 64 + ni * 16 + lr;
                float v = acc[mi][ni][r] + bias[col] + resid[(size_t)row * 1024 + col];
                out[(size_t)row * 1024 + col] = v;
            }
}

// ---------------------------------------------------------------------------
// Fused transpose_v + attn_stats.
//   blocks 0..511   : attn_stats (g, 128-row q-tile)
//   blocks 512..1535: V transpose WITH PV k-slot permutation: slot s of each
//                     64-key chunk stores key perm64(s) (see perm64 derivation)
// ---------------------------------------------------------------------------
__global__ __launch_bounds__(256) void tv_stats(
    const ushort_t* __restrict__ vb, ushort_t* __restrict__ vt,
    const ushort_t* __restrict__ qb, const ushort_t* __restrict__ kb,
    float* __restrict__ invb)
{
    __shared__ ushort_t sh[2 * 64 * 72];   // 18 KB union
    const int f = blockIdx.x;
    const int t = threadIdx.x;

    if (f >= 512) {
        // ---- transpose_v role (permuted key order) ----
        const int idx = f - 512;
        const int g   = idx & 31;
        const int lt  = idx >> 5;
#pragma unroll
        for (int it = 0; it < 2; ++it) {
            int s = t * 2 + it, row = s >> 3, sub = (s & 7) * 8;
            *reinterpret_cast<s16x8*>(&sh[row * 72 + sub]) =
                *reinterpret_cast<const s16x8*>(vb + ((size_t)(g*2048 + lt*64 + row))*64 + sub);
        }
        __syncthreads();
#pragma unroll
        for (int it = 0; it < 2; ++it) {
            int s = t * 2 + it, drow = s >> 3, sub = (s & 7) * 8;
            s16x8 o;
#pragma unroll
            for (int j = 0; j < 8; ++j) {
                int key = perm64(sub + j);
                o[j] = (short)sh[key * 72 + drow];
            }
            *reinterpret_cast<s16x8*>(vt + ((size_t)(g*64 + drow))*2048 + lt*64 + sub) = o;
        }
        return;
    }

    // ---- attn_stats role ----
#define KS(b, row, col) sh[(b) * 4608 + (row) * 72 + (col)]
    const int g  = xcd_chunk32(f);
    const int r0 = (f >> 5) * 128;
    const int w  = t >> 6;
    const int l  = t & 63;
    const int lr = l & 15;
    const int lg = l >> 4;
    const int srow0 = (t*2)   >> 3, ssub0 = ((t*2)   & 7) * 8;
    const int srow1 = (t*2+1) >> 3, ssub1 = ((t*2+1) & 7) * 8;

    s16x8 qf[2][2];
#pragma unroll
    for (int rf = 0; rf < 2; ++rf) {
        const ushort_t* qrow = qb + ((size_t)(g*2048 + r0 + w*32 + rf*16 + lr)) * 64;
        qf[rf][0] = *reinterpret_cast<const s16x8*>(qrow + lg*8);
        qf[rf][1] = *reinterpret_cast<const s16x8*>(qrow + 32 + lg*8);
    }

    *reinterpret_cast<s16x8*>(&KS(0, srow0, ssub0)) =
        *reinterpret_cast<const s16x8*>(kb + ((size_t)(g*2048 + srow0))*64 + ssub0);
    *reinterpret_cast<s16x8*>(&KS(0, srow1, ssub1)) =
        *reinterpret_cast<const s16x8*>(kb + ((size_t)(g*2048 + srow1))*64 + ssub1);
    __syncthreads();

    float lsum[2][4] = {};
    int cur = 0;

    for (int jc = 0; jc < 32; ++jc) {
        s16x8 nk0, nk1;
        if (jc < 31) {
            nk0 = *reinterpret_cast<const s16x8*>(kb + ((size_t)(g*2048 + (jc+1)*64 + srow0))*64 + ssub0);
            nk1 = *reinterpret_cast<const s16x8*>(kb + ((size_t)(g*2048 + (jc+1)*64 + srow1))*64 + ssub1);
        }
#pragma unroll
        for (int jf = 0; jf < 4; ++jf) {
            s16x8 b0 = *reinterpret_cast<const s16x8*>(&KS(cur, jf*16 + lr, lg*8));
            s16x8 b1 = *reinterpret_cast<const s16x8*>(&KS(cur, jf*16 + lr, 32 + lg*8));
#pragma unroll
            for (int rf = 0; rf < 2; ++rf) {
                f32x4 sv = {};
                sv = __builtin_amdgcn_mfma_f32_16x16x32_bf16(qf[rf][0], b0, sv, 0, 0, 0);
                sv = __builtin_amdgcn_mfma_f32_16x16x32_bf16(qf[rf][1], b1, sv, 0, 0, 0);
#pragma unroll
                for (int r = 0; r < 4; ++r)
                    lsum[rf][r] += __expf(sv[r] * 0.5f);
            }
        }
        if (jc < 31) {
            *reinterpret_cast<s16x8*>(&KS(cur^1, srow0, ssub0)) = nk0;
            *reinterpret_cast<s16x8*>(&KS(cur^1, srow1, ssub1)) = nk1;
        }
        __syncthreads();
        cur ^= 1;
    }

#pragma unroll
    for (int rf = 0; rf < 2; ++rf)
#pragma unroll
        for (int r = 0; r < 4; ++r) {
            float v = lsum[rf][r];
            v += __shfl_xor(v, 1); v += __shfl_xor(v, 2);
            v += __shfl_xor(v, 4); v += __shfl_xor(v, 8);
            if (lr == 0)
                invb[(size_t)g*2048 + r0 + w*32 + rf*16 + lg*4 + r] = 1.f / v;
        }
#undef KS
}

// ---------------------------------------------------------------------------
// attn_main: P held in REGISTERS (no Ps LDS round-trip). Swapped QK^T puts
// P[q-row lr][keys 16jf+4lg+0..3] in lane (lg,lr); PV consumes exactly those
// via the perm64 k-slot order (V pre-permuted in tv_stats). LDS 36 KB
// (Ks+Vs dbuf only) -> 4 blocks/CU, grid 1024 = exact fit.
// ---------------------------------------------------------------------------
__global__ __launch_bounds__(256) void attn_main(
    const ushort_t* __restrict__ qb, const ushort_t* __restrict__ kb,
    const ushort_t* __restrict__ vt, const float* __restrict__ invb,
    float* __restrict__ attn, ushort_t* __restrict__ ctxb)
{
    __shared__ ushort_t Ks[2][64][72];   // 18 KB
    __shared__ ushort_t Vs[2][64][72];   // 18 KB -> 36 KB total

    const int f  = blockIdx.x;
    const int g  = xcd_chunk32(f);
    const int r0 = (f >> 5) * 64;
    const int t  = threadIdx.x;
    const int w  = t >> 6;
    const int l  = t & 63;
    const int lr = l & 15;
    const int lg = l >> 4;
    const int srow0 = (t*2)   >> 3, ssub0 = ((t*2)   & 7) * 8;
    const int srow1 = (t*2+1) >> 3, ssub1 = ((t*2+1) & 7) * 8;

    s16x8 qf0, qf1;
    {
        const ushort_t* qrow = qb + ((size_t)(g*2048 + r0 + w*16 + lr)) * 64;
        qf0 = *reinterpret_cast<const s16x8*>(qrow + lg*8);
        qf1 = *reinterpret_cast<const s16x8*>(qrow + 32 + lg*8);
    }

    const float inv_s = invb[(size_t)g*2048 + r0 + w*16 + lr];
    float* arow = attn + (size_t)g*Lseq*Lseq + (size_t)(r0 + w*16 + lr)*Lseq + lg*4;

    *reinterpret_cast<s16x8*>(&Ks[0][srow0][ssub0]) =
        *reinterpret_cast<const s16x8*>(kb + ((size_t)(g*2048 + srow0))*64 + ssub0);
    *reinterpret_cast<s16x8*>(&Ks[0][srow1][ssub1]) =
        *reinterpret_cast<const s16x8*>(kb + ((size_t)(g*2048 + srow1))*64 + ssub1);
    *reinterpret_cast<s16x8*>(&Vs[0][srow0][ssub0]) =
        *reinterpret_cast<const s16x8*>(vt + ((size_t)(g*64 + srow0))*2048 + ssub0);
    *reinterpret_cast<s16x8*>(&Vs[0][srow1][ssub1]) =
        *reinterpret_cast<const s16x8*>(vt + ((size_t)(g*64 + srow1))*2048 + ssub1);
    __syncthreads();

    f32x4 ctx[4] = {};
    int cur = 0;

    for (int jc = 0; jc < 32; ++jc) {
        s16x8 nk0, nk1, nv0, nv1;
        if (jc < 31) {
            nk0 = *reinterpret_cast<const s16x8*>(kb + ((size_t)(g*2048 + (jc+1)*64 + srow0))*64 + ssub0);
            nk1 = *reinterpret_cast<const s16x8*>(kb + ((size_t)(g*2048 + (jc+1)*64 + srow1))*64 + ssub1);
            nv0 = *reinterpret_cast<const s16x8*>(vt + ((size_t)(g*64 + srow0))*2048 + (jc+1)*64 + ssub0);
            nv1 = *reinterpret_cast<const s16x8*>(vt + ((size_t)(g*64 + srow1))*2048 + (jc+1)*64 + ssub1);
        }

        // phase A: S^T = K·Q^T -> lane holds keys {jf*16+4lg..+3} of q-row lr.
        // P packed to bf16 pairs IN REGISTERS (pj), no LDS.
        uint2 pj[4];
#pragma unroll
        for (int jf = 0; jf < 4; ++jf) {
            s16x8 a0 = *reinterpret_cast<const s16x8*>(&Ks[cur][jf*16 + lr][lg*8]);
            s16x8 a1 = *reinterpret_cast<const s16x8*>(&Ks[cur][jf*16 + lr][32 + lg*8]);
            f32x4 s = {};
            s = __builtin_amdgcn_mfma_f32_16x16x32_bf16(a0, qf0, s, 0, 0, 0);
            s = __builtin_amdgcn_mfma_f32_16x16x32_bf16(a1, qf1, s, 0, 0, 0);

            float e0 = __expf(s[0] * 0.5f);
            float e1 = __expf(s[1] * 0.5f);
            float e2 = __expf(s[2] * 0.5f);
            float e3 = __expf(s[3] * 0.5f);

            f32x4 o;
            o[0] = e0 * inv_s; o[1] = e1 * inv_s; o[2] = e2 * inv_s; o[3] = e3 * inv_s;
            *reinterpret_cast<f32x4*>(arow + jc*64 + jf*16) = o;

            pj[jf].x = cvt_pk_bf16(e0, e1);
            pj[jf].y = cvt_pk_bf16(e2, e3);
        }

        // phase B: PV with register-resident P. k-slot order = perm64
        // (V pre-permuted to match). pa dwords statically indexed.
#pragma unroll
        for (int kk = 0; kk < 2; ++kk) {
            union { s16x8 v; uint2 u[2]; } pu;
            pu.u[0] = pj[2*kk];
            pu.u[1] = pj[2*kk + 1];
#pragma unroll
            for (int ni = 0; ni < 4; ++ni) {
                s16x8 bv = *reinterpret_cast<const s16x8*>(&Vs[cur][ni*16 + lr][kk*32 + lg*8]);
                ctx[ni] = __builtin_amdgcn_mfma_f32_16x16x32_bf16(pu.v, bv, ctx[ni], 0, 0, 0);
            }
        }

        if (jc < 31) {
            *reinterpret_cast<s16x8*>(&Ks[cur^1][srow0][ssub0]) = nk0;
            *reinterpret_cast<s16x8*>(&Ks[cur^1][srow1][ssub1]) = nk1;
            *reinterpret_cast<s16x8*>(&Vs[cur^1][srow0][ssub0]) = nv0;
            *reinterpret_cast<s16x8*>(&Vs[cur^1][srow1][ssub1]) = nv1;
        }
        __syncthreads();
        cur ^= 1;
    }

    // ctx write — FLAT VIEW: g*L*64 + l2*64 + d2
#pragma unroll
    for (int ni = 0; ni < 4; ++ni)
#pragma unroll
        for (int r = 0; r < 4; ++r) {
            int l2 = r0 + w*16 + lg*4 + r;
            int d2 = ni*16 + lr;
            float iv = invb[(size_t)g*2048 + l2];
            ctxb[(size_t)g*Lseq*64 + (size_t)l2*64 + d2] = f2bf(ctx[ni][r] * iv);
        }
}

// ---------------------------------------------------------------------------
// LayerNorm over D=1024, one block per row, in-place.
// ---------------------------------------------------------------------------
__global__ __launch_bounds__(256) void ln_kernel(
    float* __restrict__ x, const float* __restrict__ gamma,
    const float* __restrict__ beta, float* __restrict__ out)
{
    const int row = blockIdx.x;
    const int t   = threadIdx.x;
    const int c   = t * 4;

    float4 v = *reinterpret_cast<const float4*>(x + (size_t)row * Dmodel + c);
    float s  = v.x + v.y + v.z + v.w;
    float s2 = v.x*v.x + v.y*v.y + v.z*v.z + v.w*v.w;
    for (int off = 1; off < 64; off <<= 1) {
        s  += __shfl_xor(s, off);
        s2 += __shfl_xor(s2, off);
    }
    __shared__ float ssum[4], ssum2[4];
    int wid = t >> 6;
    if ((t & 63) == 0) { ssum[wid] = s; ssum2[wid] = s2; }
    __syncthreads();
    s  = ssum[0] + ssum[1] + ssum[2] + ssum[3];
    s2 = ssum2[0] + ssum2[1] + ssum2[2] + ssum2[3];

    float mean = s * (1.f / Dmodel);
    float var  = s2 * (1.f / Dmodel) - mean * mean;
    float rstd = rsqrtf(var + EPS_LN);

    float4 gv = *reinterpret_cast<const float4*>(gamma + c);
    float4 bv = *reinterpret_cast<const float4*>(beta + c);
    float4 o;
    o.x = (v.x - mean) * rstd * gv.x + bv.x;
    o.y = (v.y - mean) * rstd * gv.y + bv.y;
    o.z = (v.z - mean) * rstd * gv.z + bv.z;
    o.w = (v.w - mean) * rstd * gv.w + bv.w;
    *reinterpret_cast<float4*>(out + (size_t)row * Dmodel + c) = o;
}

// ---------------------------------------------------------------------------
extern "C" void kernel_launch(void* const* d_in, const int* in_sizes, int n_in,
                              void* d_out, int out_size, void* d_ws, size_t ws_size,
                              hipStream_t stream)
{
    const float* key   = (const float*)d_in[0];
    const float* value = (const float*)d_in[1];
    const float* query = (const float*)d_in[2];
    const float* Wq    = (const float*)d_in[3];
    const float* bq    = (const float*)d_in[4];
    const float* Wk    = (const float*)d_in[5];
    const float* bk    = (const float*)d_in[6];
    const float* Wv    = (const float*)d_in[7];
    const float* bv    = (const float*)d_in[8];
    const float* Wo    = (const float*)d_in[9];
    const float* bo    = (const float*)d_in[10];
    const float* gamma = (const float*)d_in[11];
    const float* beta  = (const float*)d_in[12];

    float* out  = (float*)d_out;
    float* attn = out + (size_t)MROWS * Dmodel;

    const size_t M1 = 1024 * 1024;
    ushort_t* ws   = (ushort_t*)d_ws;
    ushort_t* qb   = ws;                 // 4M
    ushort_t* kb   = ws + 4  * M1;       // 4M
    ushort_t* vb   = ws + 8  * M1;       // 4M
    ushort_t* vt   = ws + 12 * M1;       // 4M
    ushort_t* qx   = ws + 16 * M1;       // 4M (reused as ctxb after Q-GEMM)
    ushort_t* kx   = ws + 20 * M1;       // 4M (reused as invb after K-GEMM)
    ushort_t* vx   = ws + 24 * M1;       // 4M
    ushort_t* wqx  = ws + 28 * M1;       // 1M
    ushort_t* wkx  = ws + 29 * M1;       // 1M
    ushort_t* wvx  = ws + 30 * M1;       // 1M
    ushort_t* wox  = ws + 31 * M1;       // 1M  -> 64 MB total
    ushort_t* ctxb = qx;
    float*    invb = (float*)kx;

    // 1. convert everything to bf16
    CvtArgs ca;
    ca.src[0]=query; ca.dst[0]=qx;  ca.n8[0]=(int)(4*M1/8);
    ca.src[1]=key;   ca.dst[1]=kx;  ca.n8[1]=(int)(4*M1/8);
    ca.src[2]=value; ca.dst[2]=vx;  ca.n8[2]=(int)(4*M1/8);
    ca.src[3]=Wq;    ca.dst[3]=wqx; ca.n8[3]=(int)(M1/8);
    ca.src[4]=Wk;    ca.dst[4]=wkx; ca.n8[4]=(int)(M1/8);
    ca.src[5]=Wv;    ca.dst[5]=wvx; ca.n8[5]=(int)(M1/8);
    ca.src[6]=Wo;    ca.dst[6]=wox; ca.n8[6]=(int)(M1/8);
    cvt_bf16<<<dim3(512, 7), 256, 0, stream>>>(ca);

    // 2. fused Q/K/V projections, XCD-swizzled 128x128 tiles, BK=64
    QkvArgs qa;
    qa.A[0]=qx; qa.W[0]=wqx; qa.bias[0]=bq; qa.out[0]=qb;
    qa.A[1]=kx; qa.W[1]=wkx; qa.bias[1]=bk; qa.out[1]=kb;
    qa.A[2]=vx; qa.W[2]=wvx; qa.bias[2]=bv; qa.out[2]=vb;
    gemm_qkv<<<dim3(256, 1, 3), 256, 0, stream>>>(qa);

    // 3+4. fused V-transpose (perm64 key order) + softmax denominators
    tv_stats<<<dim3(1536), 256, 0, stream>>>(vb, vt, qb, kb, invb);

    // 5. attention write + PV, register-resident P (4 blocks/CU, no tail)
    attn_main<<<dim3(1024), 256, 0, stream>>>(qb, kb, vt, invb, attn, ctxb);

    // 6. output projection + residual, 64x128 tiles, BK=64
    gemm_o<<<dim3(512), 256, 0, stream>>>(ctxb, wox, bo, query, out);

    // 7. LayerNorm
    ln_kernel<<<dim3(MROWS), 256, 0, stream>>>(out, gamma, beta, out);
}

// Round 14
// 282.315 us; speedup vs baseline: 1.1288x; 1.1288x over previous
//
#include <hip/hip_runtime.h>
#include <cstddef>
#include <cstdint>

#define Lseq   2048
#define Dmodel 1024
#define NGRP   32          // B*H
#define MROWS  4096        // B*L
#define EPS_LN 1e-5f

typedef short  s16x8 __attribute__((ext_vector_type(8)));
typedef float  f32x4 __attribute__((ext_vector_type(4)));
typedef unsigned short ushort_t;

__device__ __forceinline__ ushort_t f2bf(float f) {
    union { float f; unsigned u; } v; v.f = f;
    unsigned r = v.u + 0x7FFFu + ((v.u >> 16) & 1u);   // round-to-nearest-even
    return (ushort_t)(r >> 16);
}

// packed f32x2 -> bf16x2 (RTNE, same rounding as f2bf)
__device__ __forceinline__ unsigned cvt_pk_bf16(float lo, float hi) {
    unsigned r;
    asm("v_cvt_pk_bf16_f32 %0, %1, %2" : "=v"(r) : "v"(lo), "v"(hi));
    return r;
}

// CK-idiom addrspace casts (uintptr round-trip; folded by InferAddressSpaces)
__device__ __forceinline__ void gld16(const ushort_t* g, ushort_t* lds) {
    __builtin_amdgcn_global_load_lds(
        (const __attribute__((address_space(1))) unsigned int*)(uintptr_t)g,
        (__attribute__((address_space(3))) unsigned int*)(uintptr_t)lds,
        16, 0, 0);
}

// XCD-chunked bijective remap for a 32-wide index at gridX=8-residue:
// XCD k (= f mod 8) owns values 4k..4k+3
__device__ __forceinline__ int xcd_chunk32(int f) {
    return (f & 7) * 4 + ((f >> 3) & 3);
}

// PV k-slot permutation (verified correct in round 13): slot s of a 64-key
// chunk holds key perm64(s), matching the register-resident P layout after
// swapped QK^T: lane (lg,lr), a-frag elem e -> key 32kk+(e>=4)*16+4lg+(e&3).
__device__ __forceinline__ int perm64(int s) {
    return (s & 32) + ((s & 4) << 2) + (((s >> 3) & 3) << 2) + (s & 3);
}

// ---------------------------------------------------------------------------
// Pre-convert fp32 -> bf16 for Q/K/V inputs and the 4 weight matrices.
// ---------------------------------------------------------------------------
struct CvtArgs {
    const float* src[7];
    ushort_t*    dst[7];
    int          n8[7];
};

__global__ __launch_bounds__(256) void cvt_bf16(CvtArgs a)
{
    const int ti = blockIdx.y;
    const float* __restrict__ s = a.src[ti];
    ushort_t* __restrict__    d = a.dst[ti];
    const int n8 = a.n8[ti];
    for (int i = blockIdx.x * 256 + threadIdx.x; i < n8; i += gridDim.x * 256) {
        float4 x0 = reinterpret_cast<const float4*>(s)[i * 2];
        float4 x1 = reinterpret_cast<const float4*>(s)[i * 2 + 1];
        s16x8 o;
        o[0]=f2bf(x0.x); o[1]=f2bf(x0.y); o[2]=f2bf(x0.z); o[3]=f2bf(x0.w);
        o[4]=f2bf(x1.x); o[5]=f2bf(x1.y); o[6]=f2bf(x1.z); o[7]=f2bf(x1.w);
        reinterpret_cast<s16x8*>(d)[i] = o;
    }
}

// ---------------------------------------------------------------------------
// QKV GEMM: out[M,N] = A[M,1024] @ W[N,1024]^T + bias, bf16 out.
// Tile 128x128, BK=64, 32 KB LDS. grid (256,1,3), XCD-chunked m-tiles.
// ---------------------------------------------------------------------------
struct QkvArgs {
    const ushort_t* A[3];
    const ushort_t* W[3];
    const float*    bias[3];
    ushort_t*       out[3];
};

__global__ __launch_bounds__(256) void gemm_qkv(QkvArgs a)
{
    __shared__ ushort_t As[128 * 64];   // 16 KB
    __shared__ ushort_t Bs[128 * 64];   // 16 KB
    const int z  = blockIdx.z;
    const int f  = blockIdx.x;
    const int m0 = xcd_chunk32(f) * 128;
    const int n0 = (f >> 5) * 128;

    const ushort_t* __restrict__ A = a.A[z];
    const ushort_t* __restrict__ W = a.W[z];
    const float*    __restrict__ bias = a.bias[z];
    ushort_t*       __restrict__ outv = a.out[z];

    const int t  = threadIdx.x;
    const int w  = t >> 6;
    const int l  = t & 63;
    const int lr = l & 15;
    const int lg = l >> 4;
    const int wm = w >> 1, wn = w & 1;

    const ushort_t* gA = A + (size_t)(m0 + w * 32 + (l >> 3)) * 1024 + (l & 7) * 8;
    const ushort_t* gB = W + (size_t)(n0 + w * 32 + (l >> 3)) * 1024 + (l & 7) * 8;
    ushort_t* lA = &As[(w * 32) * 64];
    ushort_t* lB = &Bs[(w * 32) * 64];

    f32x4 acc[4][4] = {};

    for (int k0 = 0; k0 < 1024; k0 += 64) {
#pragma unroll
        for (int j = 0; j < 4; ++j) {
            gld16(gA + (size_t)j * 8 * 1024 + k0, lA + j * 8 * 64);
            gld16(gB + (size_t)j * 8 * 1024 + k0, lB + j * 8 * 64);
        }
        __syncthreads();

#pragma unroll
        for (int kk = 0; kk < 2; ++kk) {
            s16x8 af[4], bf[4];
#pragma unroll
            for (int mi = 0; mi < 4; ++mi)
                af[mi] = *reinterpret_cast<const s16x8*>(&As[(wm * 64 + mi * 16 + lr) * 64 + kk * 32 + lg * 8]);
#pragma unroll
            for (int ni = 0; ni < 4; ++ni)
                bf[ni] = *reinterpret_cast<const s16x8*>(&Bs[(wn * 64 + ni * 16 + lr) * 64 + kk * 32 + lg * 8]);
#pragma unroll
            for (int mi = 0; mi < 4; ++mi)
#pragma unroll
                for (int ni = 0; ni < 4; ++ni)
                    acc[mi][ni] = __builtin_amdgcn_mfma_f32_16x16x32_bf16(af[mi], bf[ni], acc[mi][ni], 0, 0, 0);
        }
        __syncthreads();
    }

#pragma unroll
    for (int mi = 0; mi < 4; ++mi)
#pragma unroll
        for (int ni = 0; ni < 4; ++ni)
#pragma unroll
            for (int r = 0; r < 4; ++r) {
                int row = m0 + wm * 64 + mi * 16 + lg * 4 + r;
                int col = n0 + wn * 64 + ni * 16 + lr;
                outv[(size_t)row * 1024 + col] = f2bf(acc[mi][ni][r] + bias[col]);
            }
}

// ---------------------------------------------------------------------------
// Output GEMM: 64x128 tile, BK=64, fp32 out with bias+residual. 512 blocks.
// ---------------------------------------------------------------------------
__global__ __launch_bounds__(256) void gemm_o(
    const ushort_t* __restrict__ A, const ushort_t* __restrict__ W,
    const float* __restrict__ bias, const float* __restrict__ resid,
    float* __restrict__ out)
{
    __shared__ ushort_t As[64 * 64];    //  8 KB
    __shared__ ushort_t Bs[128 * 64];   // 16 KB

    const int f  = blockIdx.x;                              // 0..511
    const int m0 = ((f & 7) * 8 + ((f >> 3) & 7)) * 64;     // 64 m-tiles
    const int n0 = (f >> 6) * 128;                          // 8 n-tiles

    const int t  = threadIdx.x;
    const int w  = t >> 6;
    const int l  = t & 63;
    const int lr = l & 15;
    const int lg = l >> 4;
    const int wm = w >> 1, wn = w & 1;    // wave tile 32x64

    const ushort_t* gA = A + (size_t)(m0 + w * 16 + (l >> 3)) * 1024 + (l & 7) * 8;
    const ushort_t* gB = W + (size_t)(n0 + w * 32 + (l >> 3)) * 1024 + (l & 7) * 8;
    ushort_t* lA = &As[(w * 16) * 64];
    ushort_t* lB = &Bs[(w * 32) * 64];

    f32x4 acc[2][4] = {};

    for (int k0 = 0; k0 < 1024; k0 += 64) {
#pragma unroll
        for (int j = 0; j < 2; ++j)
            gld16(gA + (size_t)j * 8 * 1024 + k0, lA + j * 8 * 64);
#pragma unroll
        for (int j = 0; j < 4; ++j)
            gld16(gB + (size_t)j * 8 * 1024 + k0, lB + j * 8 * 64);
        __syncthreads();

#pragma unroll
        for (int kk = 0; kk < 2; ++kk) {
            s16x8 af[2], bf[4];
#pragma unroll
            for (int mi = 0; mi < 2; ++mi)
                af[mi] = *reinterpret_cast<const s16x8*>(&As[(wm * 32 + mi * 16 + lr) * 64 + kk * 32 + lg * 8]);
#pragma unroll
            for (int ni = 0; ni < 4; ++ni)
                bf[ni] = *reinterpret_cast<const s16x8*>(&Bs[(wn * 64 + ni * 16 + lr) * 64 + kk * 32 + lg * 8]);
#pragma unroll
            for (int mi = 0; mi < 2; ++mi)
#pragma unroll
                for (int ni = 0; ni < 4; ++ni)
                    acc[mi][ni] = __builtin_amdgcn_mfma_f32_16x16x32_bf16(af[mi], bf[ni], acc[mi][ni], 0, 0, 0);
        }
        __syncthreads();
    }

#pragma unroll
    for (int mi = 0; mi < 2; ++mi)
#pragma unroll
        for (int ni = 0; ni < 4; ++ni)
#pragma unroll
            for (int r = 0; r < 4; ++r) {
                int row = m0 + wm * 32 + mi * 16 + lg * 4 + r;
                int col = n0 + wn * 64 + ni * 16 + lr;
                float v = acc[mi][ni][r] + bias[col] + resid[(size_t)row * 1024 + col];
                out[(size_t)row * 1024 + col] = v;
            }
}

// ---------------------------------------------------------------------------
// Fused transpose_v + attn_stats.
//   blocks 0..511   : attn_stats (g, 128-row q-tile)
//   blocks 512..1535: V transpose WITH perm64 key order (for register-P PV)
// ---------------------------------------------------------------------------
__global__ __launch_bounds__(256) void tv_stats(
    const ushort_t* __restrict__ vb, ushort_t* __restrict__ vt,
    const ushort_t* __restrict__ qb, const ushort_t* __restrict__ kb,
    float* __restrict__ invb)
{
    __shared__ ushort_t sh[2 * 64 * 72];   // 18 KB union
    const int f = blockIdx.x;
    const int t = threadIdx.x;

    if (f >= 512) {
        // ---- transpose_v role (perm64 key order) ----
        const int idx = f - 512;
        const int g   = idx & 31;
        const int lt  = idx >> 5;
#pragma unroll
        for (int it = 0; it < 2; ++it) {
            int s = t * 2 + it, row = s >> 3, sub = (s & 7) * 8;
            *reinterpret_cast<s16x8*>(&sh[row * 72 + sub]) =
                *reinterpret_cast<const s16x8*>(vb + ((size_t)(g*2048 + lt*64 + row))*64 + sub);
        }
        __syncthreads();
#pragma unroll
        for (int it = 0; it < 2; ++it) {
            int s = t * 2 + it, drow = s >> 3, sub = (s & 7) * 8;
            s16x8 o;
#pragma unroll
            for (int j = 0; j < 8; ++j) {
                int key = perm64(sub + j);
                o[j] = (short)sh[key * 72 + drow];
            }
            *reinterpret_cast<s16x8*>(vt + ((size_t)(g*64 + drow))*2048 + lt*64 + sub) = o;
        }
        return;
    }

    // ---- attn_stats role ----
#define KS(b, row, col) sh[(b) * 4608 + (row) * 72 + (col)]
    const int g  = xcd_chunk32(f);
    const int r0 = (f >> 5) * 128;
    const int w  = t >> 6;
    const int l  = t & 63;
    const int lr = l & 15;
    const int lg = l >> 4;
    const int srow0 = (t*2)   >> 3, ssub0 = ((t*2)   & 7) * 8;
    const int srow1 = (t*2+1) >> 3, ssub1 = ((t*2+1) & 7) * 8;

    s16x8 qf[2][2];
#pragma unroll
    for (int rf = 0; rf < 2; ++rf) {
        const ushort_t* qrow = qb + ((size_t)(g*2048 + r0 + w*32 + rf*16 + lr)) * 64;
        qf[rf][0] = *reinterpret_cast<const s16x8*>(qrow + lg*8);
        qf[rf][1] = *reinterpret_cast<const s16x8*>(qrow + 32 + lg*8);
    }

    *reinterpret_cast<s16x8*>(&KS(0, srow0, ssub0)) =
        *reinterpret_cast<const s16x8*>(kb + ((size_t)(g*2048 + srow0))*64 + ssub0);
    *reinterpret_cast<s16x8*>(&KS(0, srow1, ssub1)) =
        *reinterpret_cast<const s16x8*>(kb + ((size_t)(g*2048 + srow1))*64 + ssub1);
    __syncthreads();

    float lsum[2][4] = {};
    int cur = 0;

    for (int jc = 0; jc < 32; ++jc) {
        s16x8 nk0, nk1;
        if (jc < 31) {
            nk0 = *reinterpret_cast<const s16x8*>(kb + ((size_t)(g*2048 + (jc+1)*64 + srow0))*64 + ssub0);
            nk1 = *reinterpret_cast<const s16x8*>(kb + ((size_t)(g*2048 + (jc+1)*64 + srow1))*64 + ssub1);
        }
#pragma unroll
        for (int jf = 0; jf < 4; ++jf) {
            s16x8 b0 = *reinterpret_cast<const s16x8*>(&KS(cur, jf*16 + lr, lg*8));
            s16x8 b1 = *reinterpret_cast<const s16x8*>(&KS(cur, jf*16 + lr, 32 + lg*8));
#pragma unroll
            for (int rf = 0; rf < 2; ++rf) {
                f32x4 sv = {};
                sv = __builtin_amdgcn_mfma_f32_16x16x32_bf16(qf[rf][0], b0, sv, 0, 0, 0);
                sv = __builtin_amdgcn_mfma_f32_16x16x32_bf16(qf[rf][1], b1, sv, 0, 0, 0);
#pragma unroll
                for (int r = 0; r < 4; ++r)
                    lsum[rf][r] += __expf(sv[r] * 0.5f);
            }
        }
        if (jc < 31) {
            *reinterpret_cast<s16x8*>(&KS(cur^1, srow0, ssub0)) = nk0;
            *reinterpret_cast<s16x8*>(&KS(cur^1, srow1, ssub1)) = nk1;
        }
        __syncthreads();
        cur ^= 1;
    }

#pragma unroll
    for (int rf = 0; rf < 2; ++rf)
#pragma unroll
        for (int r = 0; r < 4; ++r) {
            float v = lsum[rf][r];
            v += __shfl_xor(v, 1); v += __shfl_xor(v, 2);
            v += __shfl_xor(v, 4); v += __shfl_xor(v, 8);
            if (lr == 0)
                invb[(size_t)g*2048 + r0 + w*32 + rf*16 + lg*4 + r] = 1.f / v;
        }
#undef KS
}

// ---------------------------------------------------------------------------
// attn_main: register-resident P at ISO-OCCUPANCY (3 blocks/CU, like r12).
// Ks/Vs padding widened to [64][88] -> 44 KB LDS (row stride 176 B keeps
// fragment reads 2-way bank-free). Isolates register-P from the 4-blocks/CU
// occupancy effect that confounded r13.
// ---------------------------------------------------------------------------
__global__ __launch_bounds__(256) void attn_main(
    const ushort_t* __restrict__ qb, const ushort_t* __restrict__ kb,
    const ushort_t* __restrict__ vt, const float* __restrict__ invb,
    float* __restrict__ attn, ushort_t* __restrict__ ctxb)
{
    __shared__ ushort_t Ks[2][64][88];   // 22 KB
    __shared__ ushort_t Vs[2][64][88];   // 22 KB -> 44 KB total, 3 blocks/CU

    const int f  = blockIdx.x;
    const int g  = xcd_chunk32(f);
    const int r0 = (f >> 5) * 64;
    const int t  = threadIdx.x;
    const int w  = t >> 6;
    const int l  = t & 63;
    const int lr = l & 15;
    const int lg = l >> 4;
    const int srow0 = (t*2)   >> 3, ssub0 = ((t*2)   & 7) * 8;
    const int srow1 = (t*2+1) >> 3, ssub1 = ((t*2+1) & 7) * 8;

    s16x8 qf0, qf1;
    {
        const ushort_t* qrow = qb + ((size_t)(g*2048 + r0 + w*16 + lr)) * 64;
        qf0 = *reinterpret_cast<const s16x8*>(qrow + lg*8);
        qf1 = *reinterpret_cast<const s16x8*>(qrow + 32 + lg*8);
    }

    const float inv_s = invb[(size_t)g*2048 + r0 + w*16 + lr];
    float* arow = attn + (size_t)g*Lseq*Lseq + (size_t)(r0 + w*16 + lr)*Lseq + lg*4;

    *reinterpret_cast<s16x8*>(&Ks[0][srow0][ssub0]) =
        *reinterpret_cast<const s16x8*>(kb + ((size_t)(g*2048 + srow0))*64 + ssub0);
    *reinterpret_cast<s16x8*>(&Ks[0][srow1][ssub1]) =
        *reinterpret_cast<const s16x8*>(kb + ((size_t)(g*2048 + srow1))*64 + ssub1);
    *reinterpret_cast<s16x8*>(&Vs[0][srow0][ssub0]) =
        *reinterpret_cast<const s16x8*>(vt + ((size_t)(g*64 + srow0))*2048 + ssub0);
    *reinterpret_cast<s16x8*>(&Vs[0][srow1][ssub1]) =
        *reinterpret_cast<const s16x8*>(vt + ((size_t)(g*64 + srow1))*2048 + ssub1);
    __syncthreads();

    f32x4 ctx[4] = {};
    int cur = 0;

    for (int jc = 0; jc < 32; ++jc) {
        s16x8 nk0, nk1, nv0, nv1;
        if (jc < 31) {
            nk0 = *reinterpret_cast<const s16x8*>(kb + ((size_t)(g*2048 + (jc+1)*64 + srow0))*64 + ssub0);
            nk1 = *reinterpret_cast<const s16x8*>(kb + ((size_t)(g*2048 + (jc+1)*64 + srow1))*64 + ssub1);
            nv0 = *reinterpret_cast<const s16x8*>(vt + ((size_t)(g*64 + srow0))*2048 + (jc+1)*64 + ssub0);
            nv1 = *reinterpret_cast<const s16x8*>(vt + ((size_t)(g*64 + srow1))*2048 + (jc+1)*64 + ssub1);
        }

        // phase A: S^T = K·Q^T -> lane holds keys {jf*16+4lg..+3} of q-row lr.
        // P packed to bf16 pairs IN REGISTERS (pj), no LDS round-trip.
        uint2 pj[4];
#pragma unroll
        for (int jf = 0; jf < 4; ++jf) {
            s16x8 a0 = *reinterpret_cast<const s16x8*>(&Ks[cur][jf*16 + lr][lg*8]);
            s16x8 a1 = *reinterpret_cast<const s16x8*>(&Ks[cur][jf*16 + lr][32 + lg*8]);
            f32x4 s = {};
            s = __builtin_amdgcn_mfma_f32_16x16x32_bf16(a0, qf0, s, 0, 0, 0);
            s = __builtin_amdgcn_mfma_f32_16x16x32_bf16(a1, qf1, s, 0, 0, 0);

            float e0 = __expf(s[0] * 0.5f);
            float e1 = __expf(s[1] * 0.5f);
            float e2 = __expf(s[2] * 0.5f);
            float e3 = __expf(s[3] * 0.5f);

            f32x4 o;
            o[0] = e0 * inv_s; o[1] = e1 * inv_s; o[2] = e2 * inv_s; o[3] = e3 * inv_s;
            *reinterpret_cast<f32x4*>(arow + jc*64 + jf*16) = o;

            pj[jf].x = cvt_pk_bf16(e0, e1);
            pj[jf].y = cvt_pk_bf16(e2, e3);
        }

        // phase B: PV with register-resident P, perm64 k-slot order
        // (V pre-permuted in tv_stats). All pa dwords statically indexed.
#pragma unroll
        for (int kk = 0; kk < 2; ++kk) {
            union { s16x8 v; uint2 u[2]; } pu;
            pu.u[0] = pj[2*kk];
            pu.u[1] = pj[2*kk + 1];
#pragma unroll
            for (int ni = 0; ni < 4; ++ni) {
                s16x8 bv = *reinterpret_cast<const s16x8*>(&Vs[cur][ni*16 + lr][kk*32 + lg*8]);
                ctx[ni] = __builtin_amdgcn_mfma_f32_16x16x32_bf16(pu.v, bv, ctx[ni], 0, 0, 0);
            }
        }

        if (jc < 31) {
            *reinterpret_cast<s16x8*>(&Ks[cur^1][srow0][ssub0]) = nk0;
            *reinterpret_cast<s16x8*>(&Ks[cur^1][srow1][ssub1]) = nk1;
            *reinterpret_cast<s16x8*>(&Vs[cur^1][srow0][ssub0]) = nv0;
            *reinterpret_cast<s16x8*>(&Vs[cur^1][srow1][ssub1]) = nv1;
        }
        __syncthreads();
        cur ^= 1;
    }

    // ctx write — FLAT VIEW: g*L*64 + l2*64 + d2
#pragma unroll
    for (int ni = 0; ni < 4; ++ni)
#pragma unroll
        for (int r = 0; r < 4; ++r) {
            int l2 = r0 + w*16 + lg*4 + r;
            int d2 = ni*16 + lr;
            float iv = invb[(size_t)g*2048 + l2];
            ctxb[(size_t)g*Lseq*64 + (size_t)l2*64 + d2] = f2bf(ctx[ni][r] * iv);
        }
}

// ---------------------------------------------------------------------------
// LayerNorm over D=1024, one block per row, in-place.
// ---------------------------------------------------------------------------
__global__ __launch_bounds__(256) void ln_kernel(
    float* __restrict__ x, const float* __restrict__ gamma,
    const float* __restrict__ beta, float* __restrict__ out)
{
    const int row = blockIdx.x;
    const int t   = threadIdx.x;
    const int c   = t * 4;

    float4 v = *reinterpret_cast<const float4*>(x + (size_t)row * Dmodel + c);
    float s  = v.x + v.y + v.z + v.w;
    float s2 = v.x*v.x + v.y*v.y + v.z*v.z + v.w*v.w;
    for (int off = 1; off < 64; off <<= 1) {
        s  += __shfl_xor(s, off);
        s2 += __shfl_xor(s2, off);
    }
    __shared__ float ssum[4], ssum2[4];
    int wid = t >> 6;
    if ((t & 63) == 0) { ssum[wid] = s; ssum2[wid] = s2; }
    __syncthreads();
    s  = ssum[0] + ssum[1] + ssum[2] + ssum[3];
    s2 = ssum2[0] + ssum2[1] + ssum2[2] + ssum2[3];

    float mean = s * (1.f / Dmodel);
    float var  = s2 * (1.f / Dmodel) - mean * mean;
    float rstd = rsqrtf(var + EPS_LN);

    float4 gv = *reinterpret_cast<const float4*>(gamma + c);
    float4 bv = *reinterpret_cast<const float4*>(beta + c);
    float4 o;
    o.x = (v.x - mean) * rstd * gv.x + bv.x;
    o.y = (v.y - mean) * rstd * gv.y + bv.y;
    o.z = (v.z - mean) * rstd * gv.z + bv.z;
    o.w = (v.w - mean) * rstd * gv.w + bv.w;
    *reinterpret_cast<float4*>(out + (size_t)row * Dmodel + c) = o;
}

// ---------------------------------------------------------------------------
extern "C" void kernel_launch(void* const* d_in, const int* in_sizes, int n_in,
                              void* d_out, int out_size, void* d_ws, size_t ws_size,
                              hipStream_t stream)
{
    const float* key   = (const float*)d_in[0];
    const float* value = (const float*)d_in[1];
    const float* query = (const float*)d_in[2];
    const float* Wq    = (const float*)d_in[3];
    const float* bq    = (const float*)d_in[4];
    const float* Wk    = (const float*)d_in[5];
    const float* bk    = (const float*)d_in[6];
    const float* Wv    = (const float*)d_in[7];
    const float* bv    = (const float*)d_in[8];
    const float* Wo    = (const float*)d_in[9];
    const float* bo    = (const float*)d_in[10];
    const float* gamma = (const float*)d_in[11];
    const float* beta  = (const float*)d_in[12];

    float* out  = (float*)d_out;
    float* attn = out + (size_t)MROWS * Dmodel;

    const size_t M1 = 1024 * 1024;
    ushort_t* ws   = (ushort_t*)d_ws;
    ushort_t* qb   = ws;                 // 4M
    ushort_t* kb   = ws + 4  * M1;       // 4M
    ushort_t* vb   = ws + 8  * M1;       // 4M
    ushort_t* vt   = ws + 12 * M1;       // 4M
    ushort_t* qx   = ws + 16 * M1;       // 4M (reused as ctxb after Q-GEMM)
    ushort_t* kx   = ws + 20 * M1;       // 4M (reused as invb after K-GEMM)
    ushort_t* vx   = ws + 24 * M1;       // 4M
    ushort_t* wqx  = ws + 28 * M1;       // 1M
    ushort_t* wkx  = ws + 29 * M1;       // 1M
    ushort_t* wvx  = ws + 30 * M1;       // 1M
    ushort_t* wox  = ws + 31 * M1;       // 1M  -> 64 MB total
    ushort_t* ctxb = qx;
    float*    invb = (float*)kx;

    // 1. convert everything to bf16
    CvtArgs ca;
    ca.src[0]=query; ca.dst[0]=qx;  ca.n8[0]=(int)(4*M1/8);
    ca.src[1]=key;   ca.dst[1]=kx;  ca.n8[1]=(int)(4*M1/8);
    ca.src[2]=value; ca.dst[2]=vx;  ca.n8[2]=(int)(4*M1/8);
    ca.src[3]=Wq;    ca.dst[3]=wqx; ca.n8[3]=(int)(M1/8);
    ca.src[4]=Wk;    ca.dst[4]=wkx; ca.n8[4]=(int)(M1/8);
    ca.src[5]=Wv;    ca.dst[5]=wvx; ca.n8[5]=(int)(M1/8);
    ca.src[6]=Wo;    ca.dst[6]=wox; ca.n8[6]=(int)(M1/8);
    cvt_bf16<<<dim3(512, 7), 256, 0, stream>>>(ca);

    // 2. fused Q/K/V projections, XCD-swizzled 128x128 tiles, BK=64
    QkvArgs qa;
    qa.A[0]=qx; qa.W[0]=wqx; qa.bias[0]=bq; qa.out[0]=qb;
    qa.A[1]=kx; qa.W[1]=wkx; qa.bias[1]=bk; qa.out[1]=kb;
    qa.A[2]=vx; qa.W[2]=wvx; qa.bias[2]=bv; qa.out[2]=vb;
    gemm_qkv<<<dim3(256, 1, 3), 256, 0, stream>>>(qa);

    // 3+4. fused V-transpose (perm64 key order) + softmax denominators
    tv_stats<<<dim3(1536), 256, 0, stream>>>(vb, vt, qb, kb, invb);

    // 5. attention write + PV, register-P at 3 blocks/CU (iso-occupancy)
    attn_main<<<dim3(1024), 256, 0, stream>>>(qb, kb, vt, invb, attn, ctxb);

    // 6. output projection + residual, 64x128 tiles, BK=64
    gemm_o<<<dim3(512), 256, 0, stream>>>(ctxb, wox, bo, query, out);

    // 7. LayerNorm
    ln_kernel<<<dim3(MROWS), 256, 0, stream>>>(out, gamma, beta, out);
}

// Round 15
// 277.895 us; speedup vs baseline: 1.1467x; 1.0159x over previous
//
#include <hip/hip_runtime.h>
#include <cstddef>
#include <cstdint>

#define Lseq   2048
#define Dmodel 1024
#define NGRP   32          // B*H
#define MROWS  4096        // B*L
#define EPS_LN 1e-5f

typedef short  s16x8 __attribute__((ext_vector_type(8)));
typedef float  f32x4 __attribute__((ext_vector_type(4)));
typedef unsigned short ushort_t;

__device__ __forceinline__ ushort_t f2bf(float f) {
    union { float f; unsigned u; } v; v.f = f;
    unsigned r = v.u + 0x7FFFu + ((v.u >> 16) & 1u);   // round-to-nearest-even
    return (ushort_t)(r >> 16);
}

// packed f32x2 -> bf16x2 (RTNE, same rounding as f2bf)
__device__ __forceinline__ unsigned cvt_pk_bf16(float lo, float hi) {
    unsigned r;
    asm("v_cvt_pk_bf16_f32 %0, %1, %2" : "=v"(r) : "v"(lo), "v"(hi));
    return r;
}

// CK-idiom addrspace casts (uintptr round-trip; folded by InferAddressSpaces)
__device__ __forceinline__ void gld16(const ushort_t* g, ushort_t* lds) {
    __builtin_amdgcn_global_load_lds(
        (const __attribute__((address_space(1))) unsigned int*)(uintptr_t)g,
        (__attribute__((address_space(3))) unsigned int*)(uintptr_t)lds,
        16, 0, 0);
}

// XCD-chunked bijective remap for a 32-wide index at gridX=8-residue:
// XCD k (= f mod 8) owns values 4k..4k+3
__device__ __forceinline__ int xcd_chunk32(int f) {
    return (f & 7) * 4 + ((f >> 3) & 3);
}

// PV k-slot permutation (verified r13/r14): slot s of a 64-key chunk holds
// key perm64(s), matching the register-resident P layout after swapped QK^T.
__device__ __forceinline__ int perm64(int s) {
    return (s & 32) + ((s & 4) << 2) + (((s >> 3) & 3) << 2) + (s & 3);
}

// ---------------------------------------------------------------------------
// Pre-convert fp32 -> bf16 for Q/K/V inputs and the 4 weight matrices.
// ---------------------------------------------------------------------------
struct CvtArgs {
    const float* src[7];
    ushort_t*    dst[7];
    int          n8[7];
};

__global__ __launch_bounds__(256) void cvt_bf16(CvtArgs a)
{
    const int ti = blockIdx.y;
    const float* __restrict__ s = a.src[ti];
    ushort_t* __restrict__    d = a.dst[ti];
    const int n8 = a.n8[ti];
    for (int i = blockIdx.x * 256 + threadIdx.x; i < n8; i += gridDim.x * 256) {
        float4 x0 = reinterpret_cast<const float4*>(s)[i * 2];
        float4 x1 = reinterpret_cast<const float4*>(s)[i * 2 + 1];
        s16x8 o;
        o[0]=f2bf(x0.x); o[1]=f2bf(x0.y); o[2]=f2bf(x0.z); o[3]=f2bf(x0.w);
        o[4]=f2bf(x1.x); o[5]=f2bf(x1.y); o[6]=f2bf(x1.z); o[7]=f2bf(x1.w);
        reinterpret_cast<s16x8*>(d)[i] = o;
    }
}

// ---------------------------------------------------------------------------
// QKV GEMM: out[M,N] = A[M,1024] @ W[N,1024]^T + bias, bf16 out.
// Tile 128x128, BK=64, 32 KB LDS. grid (256,1,3), XCD-chunked m-tiles.
// ---------------------------------------------------------------------------
struct QkvArgs {
    const ushort_t* A[3];
    const ushort_t* W[3];
    const float*    bias[3];
    ushort_t*       out[3];
};

__global__ __launch_bounds__(256) void gemm_qkv(QkvArgs a)
{
    __shared__ ushort_t As[128 * 64];   // 16 KB
    __shared__ ushort_t Bs[128 * 64];   // 16 KB
    const int z  = blockIdx.z;
    const int f  = blockIdx.x;
    const int m0 = xcd_chunk32(f) * 128;
    const int n0 = (f >> 5) * 128;

    const ushort_t* __restrict__ A = a.A[z];
    const ushort_t* __restrict__ W = a.W[z];
    const float*    __restrict__ bias = a.bias[z];
    ushort_t*       __restrict__ outv = a.out[z];

    const int t  = threadIdx.x;
    const int w  = t >> 6;
    const int l  = t & 63;
    const int lr = l & 15;
    const int lg = l >> 4;
    const int wm = w >> 1, wn = w & 1;

    const ushort_t* gA = A + (size_t)(m0 + w * 32 + (l >> 3)) * 1024 + (l & 7) * 8;
    const ushort_t* gB = W + (size_t)(n0 + w * 32 + (l >> 3)) * 1024 + (l & 7) * 8;
    ushort_t* lA = &As[(w * 32) * 64];
    ushort_t* lB = &Bs[(w * 32) * 64];

    f32x4 acc[4][4] = {};

    for (int k0 = 0; k0 < 1024; k0 += 64) {
#pragma unroll
        for (int j = 0; j < 4; ++j) {
            gld16(gA + (size_t)j * 8 * 1024 + k0, lA + j * 8 * 64);
            gld16(gB + (size_t)j * 8 * 1024 + k0, lB + j * 8 * 64);
        }
        __syncthreads();

#pragma unroll
        for (int kk = 0; kk < 2; ++kk) {
            s16x8 af[4], bf[4];
#pragma unroll
            for (int mi = 0; mi < 4; ++mi)
                af[mi] = *reinterpret_cast<const s16x8*>(&As[(wm * 64 + mi * 16 + lr) * 64 + kk * 32 + lg * 8]);
#pragma unroll
            for (int ni = 0; ni < 4; ++ni)
                bf[ni] = *reinterpret_cast<const s16x8*>(&Bs[(wn * 64 + ni * 16 + lr) * 64 + kk * 32 + lg * 8]);
#pragma unroll
            for (int mi = 0; mi < 4; ++mi)
#pragma unroll
                for (int ni = 0; ni < 4; ++ni)
                    acc[mi][ni] = __builtin_amdgcn_mfma_f32_16x16x32_bf16(af[mi], bf[ni], acc[mi][ni], 0, 0, 0);
        }
        __syncthreads();
    }

#pragma unroll
    for (int mi = 0; mi < 4; ++mi)
#pragma unroll
        for (int ni = 0; ni < 4; ++ni)
#pragma unroll
            for (int r = 0; r < 4; ++r) {
                int row = m0 + wm * 64 + mi * 16 + lg * 4 + r;
                int col = n0 + wn * 64 + ni * 16 + lr;
                outv[(size_t)row * 1024 + col] = f2bf(acc[mi][ni][r] + bias[col]);
            }
}

// ---------------------------------------------------------------------------
// Output GEMM: 64x128 tile, BK=64, fp32 out with bias+residual. 512 blocks.
// ---------------------------------------------------------------------------
__global__ __launch_bounds__(256) void gemm_o(
    const ushort_t* __restrict__ A, const ushort_t* __restrict__ W,
    const float* __restrict__ bias, const float* __restrict__ resid,
    float* __restrict__ out)
{
    __shared__ ushort_t As[64 * 64];    //  8 KB
    __shared__ ushort_t Bs[128 * 64];   // 16 KB

    const int f  = blockIdx.x;                              // 0..511
    const int m0 = ((f & 7) * 8 + ((f >> 3) & 7)) * 64;     // 64 m-tiles
    const int n0 = (f >> 6) * 128;                          // 8 n-tiles

    const int t  = threadIdx.x;
    const int w  = t >> 6;
    const int l  = t & 63;
    const int lr = l & 15;
    const int lg = l >> 4;
    const int wm = w >> 1, wn = w & 1;    // wave tile 32x64

    const ushort_t* gA = A + (size_t)(m0 + w * 16 + (l >> 3)) * 1024 + (l & 7) * 8;
    const ushort_t* gB = W + (size_t)(n0 + w * 32 + (l >> 3)) * 1024 + (l & 7) * 8;
    ushort_t* lA = &As[(w * 16) * 64];
    ushort_t* lB = &Bs[(w * 32) * 64];

    f32x4 acc[2][4] = {};

    for (int k0 = 0; k0 < 1024; k0 += 64) {
#pragma unroll
        for (int j = 0; j < 2; ++j)
            gld16(gA + (size_t)j * 8 * 1024 + k0, lA + j * 8 * 64);
#pragma unroll
        for (int j = 0; j < 4; ++j)
            gld16(gB + (size_t)j * 8 * 1024 + k0, lB + j * 8 * 64);
        __syncthreads();

#pragma unroll
        for (int kk = 0; kk < 2; ++kk) {
            s16x8 af[2], bf[4];
#pragma unroll
            for (int mi = 0; mi < 2; ++mi)
                af[mi] = *reinterpret_cast<const s16x8*>(&As[(wm * 32 + mi * 16 + lr) * 64 + kk * 32 + lg * 8]);
#pragma unroll
            for (int ni = 0; ni < 4; ++ni)
                bf[ni] = *reinterpret_cast<const s16x8*>(&Bs[(wn * 64 + ni * 16 + lr) * 64 + kk * 32 + lg * 8]);
#pragma unroll
            for (int mi = 0; mi < 2; ++mi)
#pragma unroll
                for (int ni = 0; ni < 4; ++ni)
                    acc[mi][ni] = __builtin_amdgcn_mfma_f32_16x16x32_bf16(af[mi], bf[ni], acc[mi][ni], 0, 0, 0);
        }
        __syncthreads();
    }

#pragma unroll
    for (int mi = 0; mi < 2; ++mi)
#pragma unroll
        for (int ni = 0; ni < 4; ++ni)
#pragma unroll
            for (int r = 0; r < 4; ++r) {
                int row = m0 + wm * 32 + mi * 16 + lg * 4 + r;
                int col = n0 + wn * 64 + ni * 16 + lr;
                float v = acc[mi][ni][r] + bias[col] + resid[(size_t)row * 1024 + col];
                out[(size_t)row * 1024 + col] = v;
            }
}

// ---------------------------------------------------------------------------
// V transpose with perm64 key order: vb[32][2048][64] -> vt[32][64][2048]
// ---------------------------------------------------------------------------
__global__ __launch_bounds__(256) void transpose_v(
    const ushort_t* __restrict__ vb, ushort_t* __restrict__ vt)
{
    __shared__ ushort_t tile[64][72];
    const int g  = blockIdx.x;
    const int lt = blockIdx.y;
    const int t  = threadIdx.x;
#pragma unroll
    for (int it = 0; it < 2; ++it) {
        int s = t * 2 + it, row = s >> 3, sub = (s & 7) * 8;
        *reinterpret_cast<s16x8*>(&tile[row][sub]) =
            *reinterpret_cast<const s16x8*>(vb + ((size_t)(g*2048 + lt*64 + row))*64 + sub);
    }
    __syncthreads();
#pragma unroll
    for (int it = 0; it < 2; ++it) {
        int s = t * 2 + it, drow = s >> 3, sub = (s & 7) * 8;
        s16x8 o;
#pragma unroll
        for (int j = 0; j < 8; ++j) {
            int key = perm64(sub + j);
            o[j] = (short)tile[key][drow];
        }
        *reinterpret_cast<s16x8*>(vt + ((size_t)(g*64 + drow))*2048 + lt*64 + sub) = o;
    }
}

// ---------------------------------------------------------------------------
// attn_main (stats FUSED): prologue computes row sums with mfma(Q,K) using
// the SAME Q-fragment registers (A/B frag layouts share lane&15 / lane>>4
// indexing), shares 1/sum via a 256 B LDS wsum; main phase is r14's
// register-P swapped QK^T + perm64 PV. 44.25 KB LDS -> 3 blocks/CU.
// Tail blocks' prologue (compute) overlaps other blocks' store phase.
// ---------------------------------------------------------------------------
__global__ __launch_bounds__(256) void attn_main(
    const ushort_t* __restrict__ qb, const ushort_t* __restrict__ kb,
    const ushort_t* __restrict__ vt,
    float* __restrict__ attn, ushort_t* __restrict__ ctxb)
{
    __shared__ ushort_t Ks[2][64][88];   // 22 KB
    __shared__ ushort_t Vs[2][64][88];   // 22 KB
    __shared__ float    wsum[4][16];     // 256 B -> 44.25 KB total

    const int f  = blockIdx.x;
    const int g  = xcd_chunk32(f);
    const int r0 = (f >> 5) * 64;
    const int t  = threadIdx.x;
    const int w  = t >> 6;
    const int l  = t & 63;
    const int lr = l & 15;
    const int lg = l >> 4;
    const int srow0 = (t*2)   >> 3, ssub0 = ((t*2)   & 7) * 8;
    const int srow1 = (t*2+1) >> 3, ssub1 = ((t*2+1) & 7) * 8;

    s16x8 qf0, qf1;
    {
        const ushort_t* qrow = qb + ((size_t)(g*2048 + r0 + w*16 + lr)) * 64;
        qf0 = *reinterpret_cast<const s16x8*>(qrow + lg*8);
        qf1 = *reinterpret_cast<const s16x8*>(qrow + 32 + lg*8);
    }

    // ============== prologue: row sums (Q as A-operand) ==============
    *reinterpret_cast<s16x8*>(&Ks[0][srow0][ssub0]) =
        *reinterpret_cast<const s16x8*>(kb + ((size_t)(g*2048 + srow0))*64 + ssub0);
    *reinterpret_cast<s16x8*>(&Ks[0][srow1][ssub1]) =
        *reinterpret_cast<const s16x8*>(kb + ((size_t)(g*2048 + srow1))*64 + ssub1);
    __syncthreads();

    float lsum[4] = {0.f, 0.f, 0.f, 0.f};
    int cur = 0;

    for (int jc = 0; jc < 32; ++jc) {
        s16x8 nk0, nk1;
        if (jc < 31) {
            nk0 = *reinterpret_cast<const s16x8*>(kb + ((size_t)(g*2048 + (jc+1)*64 + srow0))*64 + ssub0);
            nk1 = *reinterpret_cast<const s16x8*>(kb + ((size_t)(g*2048 + (jc+1)*64 + srow1))*64 + ssub1);
        }
#pragma unroll
        for (int jf = 0; jf < 4; ++jf) {
            s16x8 b0 = *reinterpret_cast<const s16x8*>(&Ks[cur][jf*16 + lr][lg*8]);
            s16x8 b1 = *reinterpret_cast<const s16x8*>(&Ks[cur][jf*16 + lr][32 + lg*8]);
            f32x4 sv = {};
            sv = __builtin_amdgcn_mfma_f32_16x16x32_bf16(qf0, b0, sv, 0, 0, 0);
            sv = __builtin_amdgcn_mfma_f32_16x16x32_bf16(qf1, b1, sv, 0, 0, 0);
#pragma unroll
            for (int r = 0; r < 4; ++r)
                lsum[r] += __expf(sv[r] * 0.5f);
        }
        if (jc < 31) {
            *reinterpret_cast<s16x8*>(&Ks[cur^1][srow0][ssub0]) = nk0;
            *reinterpret_cast<s16x8*>(&Ks[cur^1][srow1][ssub1]) = nk1;
        }
        __syncthreads();
        cur ^= 1;
    }
    // reduce over key-lanes (lr axis) and share inv via LDS
#pragma unroll
    for (int r = 0; r < 4; ++r) {
        float v = lsum[r];
        v += __shfl_xor(v, 1); v += __shfl_xor(v, 2);
        v += __shfl_xor(v, 4); v += __shfl_xor(v, 8);
        if (lr == 0) wsum[w][lg*4 + r] = 1.f / v;
    }
    __syncthreads();   // wsum visible; Ks free for restaging (cur == 0 again)

    const float inv_s = wsum[w][lr];
    float* arow = attn + (size_t)g*Lseq*Lseq + (size_t)(r0 + w*16 + lr)*Lseq + lg*4;

    // ============== main: write + PV (register-P, perm64) ==============
    *reinterpret_cast<s16x8*>(&Ks[0][srow0][ssub0]) =
        *reinterpret_cast<const s16x8*>(kb + ((size_t)(g*2048 + srow0))*64 + ssub0);
    *reinterpret_cast<s16x8*>(&Ks[0][srow1][ssub1]) =
        *reinterpret_cast<const s16x8*>(kb + ((size_t)(g*2048 + srow1))*64 + ssub1);
    *reinterpret_cast<s16x8*>(&Vs[0][srow0][ssub0]) =
        *reinterpret_cast<const s16x8*>(vt + ((size_t)(g*64 + srow0))*2048 + ssub0);
    *reinterpret_cast<s16x8*>(&Vs[0][srow1][ssub1]) =
        *reinterpret_cast<const s16x8*>(vt + ((size_t)(g*64 + srow1))*2048 + ssub1);
    __syncthreads();

    f32x4 ctx[4] = {};
    cur = 0;

    for (int jc = 0; jc < 32; ++jc) {
        s16x8 nk0, nk1, nv0, nv1;
        if (jc < 31) {
            nk0 = *reinterpret_cast<const s16x8*>(kb + ((size_t)(g*2048 + (jc+1)*64 + srow0))*64 + ssub0);
            nk1 = *reinterpret_cast<const s16x8*>(kb + ((size_t)(g*2048 + (jc+1)*64 + srow1))*64 + ssub1);
            nv0 = *reinterpret_cast<const s16x8*>(vt + ((size_t)(g*64 + srow0))*2048 + (jc+1)*64 + ssub0);
            nv1 = *reinterpret_cast<const s16x8*>(vt + ((size_t)(g*64 + srow1))*2048 + (jc+1)*64 + ssub1);
        }

        // phase A: S^T = K·Q^T -> lane holds keys {jf*16+4lg..+3} of q-row lr.
        uint2 pj[4];
#pragma unroll
        for (int jf = 0; jf < 4; ++jf) {
            s16x8 a0 = *reinterpret_cast<const s16x8*>(&Ks[cur][jf*16 + lr][lg*8]);
            s16x8 a1 = *reinterpret_cast<const s16x8*>(&Ks[cur][jf*16 + lr][32 + lg*8]);
            f32x4 s = {};
            s = __builtin_amdgcn_mfma_f32_16x16x32_bf16(a0, qf0, s, 0, 0, 0);
            s = __builtin_amdgcn_mfma_f32_16x16x32_bf16(a1, qf1, s, 0, 0, 0);

            float e0 = __expf(s[0] * 0.5f);
            float e1 = __expf(s[1] * 0.5f);
            float e2 = __expf(s[2] * 0.5f);
            float e3 = __expf(s[3] * 0.5f);

            f32x4 o;
            o[0] = e0 * inv_s; o[1] = e1 * inv_s; o[2] = e2 * inv_s; o[3] = e3 * inv_s;
            *reinterpret_cast<f32x4*>(arow + jc*64 + jf*16) = o;

            pj[jf].x = cvt_pk_bf16(e0, e1);
            pj[jf].y = cvt_pk_bf16(e2, e3);
        }

        // phase B: PV with register-resident P, perm64 k-slot order.
#pragma unroll
        for (int kk = 0; kk < 2; ++kk) {
            union { s16x8 v; uint2 u[2]; } pu;
            pu.u[0] = pj[2*kk];
            pu.u[1] = pj[2*kk + 1];
#pragma unroll
            for (int ni = 0; ni < 4; ++ni) {
                s16x8 bv = *reinterpret_cast<const s16x8*>(&Vs[cur][ni*16 + lr][kk*32 + lg*8]);
                ctx[ni] = __builtin_amdgcn_mfma_f32_16x16x32_bf16(pu.v, bv, ctx[ni], 0, 0, 0);
            }
        }

        if (jc < 31) {
            *reinterpret_cast<s16x8*>(&Ks[cur^1][srow0][ssub0]) = nk0;
            *reinterpret_cast<s16x8*>(&Ks[cur^1][srow1][ssub1]) = nk1;
            *reinterpret_cast<s16x8*>(&Vs[cur^1][srow0][ssub0]) = nv0;
            *reinterpret_cast<s16x8*>(&Vs[cur^1][srow1][ssub1]) = nv1;
        }
        __syncthreads();
        cur ^= 1;
    }

    // ctx write — FLAT VIEW: g*L*64 + l2*64 + d2
#pragma unroll
    for (int ni = 0; ni < 4; ++ni)
#pragma unroll
        for (int r = 0; r < 4; ++r) {
            int l2 = r0 + w*16 + lg*4 + r;
            int d2 = ni*16 + lr;
            float iv = wsum[w][lg*4 + r];
            ctxb[(size_t)g*Lseq*64 + (size_t)l2*64 + d2] = f2bf(ctx[ni][r] * iv);
        }
}

// ---------------------------------------------------------------------------
// LayerNorm over D=1024, one block per row, in-place.
// ---------------------------------------------------------------------------
__global__ __launch_bounds__(256) void ln_kernel(
    float* __restrict__ x, const float* __restrict__ gamma,
    const float* __restrict__ beta, float* __restrict__ out)
{
    const int row = blockIdx.x;
    const int t   = threadIdx.x;
    const int c   = t * 4;

    float4 v = *reinterpret_cast<const float4*>(x + (size_t)row * Dmodel + c);
    float s  = v.x + v.y + v.z + v.w;
    float s2 = v.x*v.x + v.y*v.y + v.z*v.z + v.w*v.w;
    for (int off = 1; off < 64; off <<= 1) {
        s  += __shfl_xor(s, off);
        s2 += __shfl_xor(s2, off);
    }
    __shared__ float ssum[4], ssum2[4];
    int wid = t >> 6;
    if ((t & 63) == 0) { ssum[wid] = s; ssum2[wid] = s2; }
    __syncthreads();
    s  = ssum[0] + ssum[1] + ssum[2] + ssum[3];
    s2 = ssum2[0] + ssum2[1] + ssum2[2] + ssum2[3];

    float mean = s * (1.f / Dmodel);
    float var  = s2 * (1.f / Dmodel) - mean * mean;
    float rstd = rsqrtf(var + EPS_LN);

    float4 gv = *reinterpret_cast<const float4*>(gamma + c);
    float4 bv = *reinterpret_cast<const float4*>(beta + c);
    float4 o;
    o.x = (v.x - mean) * rstd * gv.x + bv.x;
    o.y = (v.y - mean) * rstd * gv.y + bv.y;
    o.z = (v.z - mean) * rstd * gv.z + bv.z;
    o.w = (v.w - mean) * rstd * gv.w + bv.w;
    *reinterpret_cast<float4*>(out + (size_t)row * Dmodel + c) = o;
}

// ---------------------------------------------------------------------------
extern "C" void kernel_launch(void* const* d_in, const int* in_sizes, int n_in,
                              void* d_out, int out_size, void* d_ws, size_t ws_size,
                              hipStream_t stream)
{
    const float* key   = (const float*)d_in[0];
    const float* value = (const float*)d_in[1];
    const float* query = (const float*)d_in[2];
    const float* Wq    = (const float*)d_in[3];
    const float* bq    = (const float*)d_in[4];
    const float* Wk    = (const float*)d_in[5];
    const float* bk    = (const float*)d_in[6];
    const float* Wv    = (const float*)d_in[7];
    const float* bv    = (const float*)d_in[8];
    const float* Wo    = (const float*)d_in[9];
    const float* bo    = (const float*)d_in[10];
    const float* gamma = (const float*)d_in[11];
    const float* beta  = (const float*)d_in[12];

    float* out  = (float*)d_out;
    float* attn = out + (size_t)MROWS * Dmodel;

    const size_t M1 = 1024 * 1024;
    ushort_t* ws   = (ushort_t*)d_ws;
    ushort_t* qb   = ws;                 // 4M
    ushort_t* kb   = ws + 4  * M1;       // 4M
    ushort_t* vb   = ws + 8  * M1;       // 4M
    ushort_t* vt   = ws + 12 * M1;       // 4M
    ushort_t* qx   = ws + 16 * M1;       // 4M (reused as ctxb after Q-GEMM)
    ushort_t* kx   = ws + 20 * M1;       // 4M
    ushort_t* vx   = ws + 24 * M1;       // 4M
    ushort_t* wqx  = ws + 28 * M1;       // 1M
    ushort_t* wkx  = ws + 29 * M1;       // 1M
    ushort_t* wvx  = ws + 30 * M1;       // 1M
    ushort_t* wox  = ws + 31 * M1;       // 1M  -> 64 MB total
    ushort_t* ctxb = qx;

    // 1. convert everything to bf16
    CvtArgs ca;
    ca.src[0]=query; ca.dst[0]=qx;  ca.n8[0]=(int)(4*M1/8);
    ca.src[1]=key;   ca.dst[1]=kx;  ca.n8[1]=(int)(4*M1/8);
    ca.src[2]=value; ca.dst[2]=vx;  ca.n8[2]=(int)(4*M1/8);
    ca.src[3]=Wq;    ca.dst[3]=wqx; ca.n8[3]=(int)(M1/8);
    ca.src[4]=Wk;    ca.dst[4]=wkx; ca.n8[4]=(int)(M1/8);
    ca.src[5]=Wv;    ca.dst[5]=wvx; ca.n8[5]=(int)(M1/8);
    ca.src[6]=Wo;    ca.dst[6]=wox; ca.n8[6]=(int)(M1/8);
    cvt_bf16<<<dim3(512, 7), 256, 0, stream>>>(ca);

    // 2. fused Q/K/V projections, XCD-swizzled 128x128 tiles, BK=64
    QkvArgs qa;
    qa.A[0]=qx; qa.W[0]=wqx; qa.bias[0]=bq; qa.out[0]=qb;
    qa.A[1]=kx; qa.W[1]=wkx; qa.bias[1]=bk; qa.out[1]=kb;
    qa.A[2]=vx; qa.W[2]=wvx; qa.bias[2]=bv; qa.out[2]=vb;
    gemm_qkv<<<dim3(256, 1, 3), 256, 0, stream>>>(qa);

    // 3. V transpose (perm64 key order)
    transpose_v<<<dim3(NGRP, Lseq/64), 256, 0, stream>>>(vb, vt);

    // 4. attention: fused stats prologue + write + PV (3 blocks/CU)
    attn_main<<<dim3(1024), 256, 0, stream>>>(qb, kb, vt, attn, ctxb);

    // 5. output projection + residual, 64x128 tiles, BK=64
    gemm_o<<<dim3(512), 256, 0, stream>>>(ctxb, wox, bo, query, out);

    // 6. LayerNorm
    ln_kernel<<<dim3(MROWS), 256, 0, stream>>>(out, gamma, beta, out);
}